// Round 1
// baseline (84.253 us; speedup 1.0000x reference)
//
#include <hip/hip_runtime.h>

// MostPopularEncoder: B=32, L=2048, C=1000
// out[0] = hiddens [B, L, 2] (avg_delta, running_mode), out[1] = same flat data.
//
// avg_delta[b,t] = (ts[b,t] - ts[b,0]) / (t+1)   (cumsum of diffs telescopes)
// running mode  = lexicographic prefix-max over positions of (cnt[t], 999-lab[t])
//   where cnt[t] = occurrence rank of labels[t] in labels[0..t] (1-based).
// Proof sketch: at time t let M = max class count, c* = smallest class with M.
//   c*'s last occurrence s* <= t has cnt[s*] = M, key (M, 999-c*).
//   Any s<=t has cnt[s] <= M; among cnt[s]==M, lab[s] attains M so lab[s]>=c*.
//   Hence the prefix max is exactly (M, 999-c*).  Ties -> smallest label,
//   matching jnp.argmax first-index semantics.

#define SEQ_B 32
#define SEQ_L 2048
#define NCLASS 1000

__global__ __launch_bounds__(64) void mpe_kernel(const float* __restrict__ ts,
                                                 const int* __restrict__ labels,
                                                 float* __restrict__ out) {
    __shared__ int counts[NCLASS];

    const int b    = blockIdx.x;
    const int lane = threadIdx.x;  // 0..63, single wave per block

    // zero the per-sequence histogram
    for (int i = lane; i < NCLASS; i += 64) counts[i] = 0;
    __syncthreads();

    const float ts0 = ts[b * SEQ_L];  // broadcast load

    // running best key: (cnt << 10) | (999 - lab); cnt=0 so any element beats it
    unsigned int best_key = 0u;

    const unsigned long long lt_mask =
        (lane == 0) ? 0ull : (~0ull >> (64 - lane));

    for (int c = 0; c < SEQ_L / 64; ++c) {
        const int t   = c * 64 + lane;
        const int idx = b * SEQ_L + t;
        const int lab = labels[idx];

        // equality mask across the wave via 10 bit-ballots (lab < 1024)
        unsigned long long eq = ~0ull;
#pragma unroll
        for (int bit = 0; bit < 10; ++bit) {
            unsigned long long bb = __ballot((lab >> bit) & 1);
            eq &= ((lab >> bit) & 1) ? bb : ~bb;
        }

        const int  rank    = __popcll(eq & lt_mask);       // earlier equal lanes
        const bool is_last = (((eq >> lane) >> 1) == 0ull); // no later equal lane

        const int base = counts[lab];      // equal-label lanes broadcast-read
        const int cnt  = base + rank + 1;  // 1-based occurrence rank in prefix
        if (is_last) counts[lab] = cnt;    // distinct labels -> distinct addrs

        unsigned int key = ((unsigned int)cnt << 10) | (unsigned int)(999 - lab);
        key = key > best_key ? key : best_key;

        // inclusive prefix max across the wave (6 shfl_up steps)
#pragma unroll
        for (int d = 1; d < 64; d <<= 1) {
            unsigned int other = (unsigned int)__shfl_up((int)key, d, 64);
            if (lane >= d && other > key) key = other;
        }
        best_key = (unsigned int)__shfl((int)key, 63, 64);

        const float top_lab = (float)(999 - (int)(key & 1023u));
        const float avg     = (ts[idx] - ts0) / (float)(t + 1);

        float2 o = make_float2(avg, top_lab);
        float2* o2 = (float2*)out;
        o2[idx] = o;                     // output 0: [B, L, 2]
        o2[SEQ_B * SEQ_L + idx] = o;     // output 1: [1, B, L, 2] (same flat data)
    }
}

extern "C" void kernel_launch(void* const* d_in, const int* in_sizes, int n_in,
                              void* d_out, int out_size, void* d_ws, size_t ws_size,
                              hipStream_t stream) {
    const float* ts     = (const float*)d_in[0];
    const int*   labels = (const int*)d_in[1];
    float*       out    = (float*)d_out;

    mpe_kernel<<<dim3(SEQ_B), dim3(64), 0, stream>>>(ts, labels, out);
}

// Round 2
// 60.526 us; speedup vs baseline: 1.3920x; 1.3920x over previous
//
#include <hip/hip_runtime.h>

// MostPopularEncoder: B=32, L=2048, C=1000
// out[0] = hiddens [B, L, 2] (avg_delta, running_mode); out[1] = same flat data.
//
// avg_delta[b,t] = (ts[b,t] - ts[b,0]) / (t+1)   (cumsum of diffs telescopes)
// running mode  = lexicographic prefix-max over positions of key(t) =
//   (cnt[t] << 10) | (999 - lab[t]),  cnt[t] = occurrence rank of labels[t]
//   in labels[0..t] (1-based).  Ties resolve to smallest label == jnp.argmax.
//
// R2: one 1024-thread block (16 waves) per sequence. Wave w owns segment
// [w*128, (w+1)*128): local ranks via 10-bit ballot equality masks (2 serial
// 64-chunks), per-wave LDS histogram; then cross-wave base = sum of earlier
// waves' histograms; then block-wide prefix-max scan of keys.

#define SEQ_B 32
#define SEQ_L 2048
#define NCLASS 1000
#define NWAVE 16
#define SEG 128

__global__ __launch_bounds__(1024) void mpe_kernel(const float* __restrict__ ts,
                                                   const int* __restrict__ labels,
                                                   float* __restrict__ out) {
    __shared__ int hist[NWAVE][NCLASS];        // 64 KB
    __shared__ unsigned int key_s[SEQ_L];      // 8 KB
    __shared__ unsigned int wave_tot[NWAVE];

    const int tid  = threadIdx.x;
    const int lane = tid & 63;
    const int w    = tid >> 6;
    const int b    = blockIdx.x;

    // zero histograms
    for (int i = tid; i < NWAVE * NCLASS; i += 1024) ((int*)hist)[i] = 0;
    __syncthreads();

    const unsigned long long lt_mask =
        (lane == 0) ? 0ull : (~0ull >> (64 - lane));

    // ---- Pass A: local occurrence ranks within this wave's 128-elem segment
    int lab_r[2];
    int cnt_r[2];
#pragma unroll
    for (int c = 0; c < 2; ++c) {
        const int t   = w * SEG + c * 64 + lane;
        const int lab = labels[b * SEQ_L + t];

        unsigned long long eq = ~0ull;  // lanes with equal label (10 ballots)
#pragma unroll
        for (int bit = 0; bit < 10; ++bit) {
            unsigned long long bb = __ballot((lab >> bit) & 1);
            eq &= ((lab >> bit) & 1) ? bb : ~bb;
        }

        const int  rank    = __popcll(eq & lt_mask);        // earlier equal lanes
        const bool is_last = (((eq >> lane) >> 1) == 0ull);  // highest equal lane

        const int base = hist[w][lab];   // equal-label lanes broadcast-read
        cnt_r[c] = base + rank + 1;      // local 1-based rank in segment
        lab_r[c] = lab;
        if (is_last) hist[w][lab] = base + __popcll(eq);  // distinct addrs
    }
    __syncthreads();

    // ---- Pass B: add counts from earlier segments, build packed keys
#pragma unroll
    for (int c = 0; c < 2; ++c) {
        int base = 0;
        for (int w2 = 0; w2 < w; ++w2) base += hist[w2][lab_r[c]];
        const int cnt = cnt_r[c] + base;  // global 1-based occurrence rank
        key_s[w * SEG + c * 64 + lane] =
            ((unsigned int)cnt << 10) | (unsigned int)(999 - lab_r[c]);
    }
    __syncthreads();

    // ---- Pass C: block inclusive prefix-max over 2048 keys (pair layout)
    const unsigned int k0 = key_s[2 * tid];
    const unsigned int k1 = key_s[2 * tid + 1];
    const unsigned int p  = k0 > k1 ? k0 : k1;

    unsigned int scan = p;  // inclusive wave scan over pair-maxes
#pragma unroll
    for (int d = 1; d < 64; d <<= 1) {
        unsigned int o = (unsigned int)__shfl_up((int)scan, d, 64);
        if (lane >= d && o > scan) scan = o;
    }
    if (lane == 63) wave_tot[w] = scan;
    unsigned int excl = (unsigned int)__shfl_up((int)scan, 1, 64);
    if (lane == 0) excl = 0;
    __syncthreads();

    unsigned int woff = 0;  // max over earlier waves' totals
    for (int w2 = 0; w2 < w; ++w2) {
        const unsigned int v = wave_tot[w2];
        if (v > woff) woff = v;
    }
    const unsigned int pre = woff > excl ? woff : excl;  // before elem 2*tid
    const unsigned int s0  = pre > k0 ? pre : k0;
    const unsigned int s1  = s0 > k1 ? s0 : k1;

    // ---- epilogue: avg_delta + mode, coalesced float4 stores (x2 outputs)
    const float  ts0 = ts[b * SEQ_L];
    const float2 tsv = ((const float2*)(ts + b * SEQ_L))[tid];
    const float  avg0 = (tsv.x - ts0) / (float)(2 * tid + 1);
    const float  avg1 = (tsv.y - ts0) / (float)(2 * tid + 2);
    const float  m0   = (float)(999 - (int)(s0 & 1023u));
    const float  m1   = (float)(999 - (int)(s1 & 1023u));

    const float4 o = make_float4(avg0, m0, avg1, m1);
    float4* o4 = (float4*)out;
    o4[b * (SEQ_L / 2) + tid] = o;                               // output 0
    o4[SEQ_B * (SEQ_L / 2) + b * (SEQ_L / 2) + tid] = o;         // output 1
}

extern "C" void kernel_launch(void* const* d_in, const int* in_sizes, int n_in,
                              void* d_out, int out_size, void* d_ws, size_t ws_size,
                              hipStream_t stream) {
    const float* ts     = (const float*)d_in[0];
    const int*   labels = (const int*)d_in[1];
    float*       out    = (float*)d_out;

    mpe_kernel<<<dim3(SEQ_B), dim3(1024), 0, stream>>>(ts, labels, out);
}

// Round 3
// 60.301 us; speedup vs baseline: 1.3972x; 1.0037x over previous
//
#include <hip/hip_runtime.h>

// MostPopularEncoder: B=32, L=2048, C=1000
// out[0] = hiddens [B, L, 2] (avg_delta, running_mode); out[1] = same flat data.
//
// avg_delta[b,t] = (ts[b,t] - ts[b,0]) / (t+1)   (cumsum of diffs telescopes)
// running mode  = lexicographic prefix-max over positions of key(t) =
//   (cnt[t] << 10) | (999 - lab[t]),  cnt[t] = occurrence rank of labels[t]
//   in labels[0..t] (1-based).  Ties resolve to smallest label == jnp.argmax.
//
// R3: one 1024-thread block (16 waves) per sequence; wave w owns positions
// [w*128, (w+1)*128) as two 64-chunks. ushort per-wave histograms (32 KB),
// in-place per-chunk shfl prefix-max scans + 32-entry chunk-total combine
// (no key staging array, 3 barriers instead of 4).

#define SEQ_B 32
#define SEQ_L 2048
#define NCLASS 1000
#define NWAVE 16

__global__ __launch_bounds__(1024) void mpe_kernel(const float* __restrict__ ts,
                                                   const int* __restrict__ labels,
                                                   float* __restrict__ out) {
    __shared__ unsigned short hist[NWAVE][NCLASS];  // 32 KB; counts <= 2048 fit
    __shared__ unsigned int chunk_tot[2 * NWAVE];   // inclusive max per 64-chunk

    const int tid  = threadIdx.x;
    const int lane = tid & 63;
    const int w    = tid >> 6;
    const int b    = blockIdx.x;

    // zero histograms (flat dword writes over 16000 ushorts = 8000 dwords)
    for (int i = tid; i < NWAVE * NCLASS / 2; i += 1024) ((unsigned int*)hist)[i] = 0u;
    __syncthreads();

    const unsigned long long lt_mask =
        (lane == 0) ? 0ull : (~0ull >> (64 - lane));

    // ---- Pass A: local occurrence ranks within this wave's two 64-chunks
    int lab_r[2];
    int cnt_r[2];
#pragma unroll
    for (int c = 0; c < 2; ++c) {
        const int t   = w * 128 + c * 64 + lane;
        const int lab = labels[b * SEQ_L + t];

        unsigned long long eq = ~0ull;  // lanes with equal label (10 ballots)
#pragma unroll
        for (int bit = 0; bit < 10; ++bit) {
            unsigned long long bb = __ballot((lab >> bit) & 1);
            eq &= ((lab >> bit) & 1) ? bb : ~bb;
        }

        const int  rank    = __popcll(eq & lt_mask);        // earlier equal lanes
        const bool is_last = (((eq >> lane) >> 1) == 0ull);  // highest equal lane

        const int base = (int)hist[w][lab];  // equal-label lanes broadcast-read
        cnt_r[c] = base + rank + 1;          // local 1-based rank in segment
        lab_r[c] = lab;
        if (is_last) hist[w][lab] = (unsigned short)(base + __popcll(eq));
    }
    __syncthreads();

    // ---- Pass B: add counts from earlier waves' segments, pack keys
    unsigned int key[2];
#pragma unroll
    for (int c = 0; c < 2; ++c) {
        int base = 0;
        for (int w2 = 0; w2 < w; ++w2) base += (int)hist[w2][lab_r[c]];
        const int cnt = cnt_r[c] + base;  // global 1-based occurrence rank
        key[c] = ((unsigned int)cnt << 10) | (unsigned int)(999 - lab_r[c]);
    }

    // ---- Pass C: in-place inclusive prefix-max, chunk-local then cross-chunk
    unsigned int scan[2] = {key[0], key[1]};
#pragma unroll
    for (int d = 1; d < 64; d <<= 1) {
        unsigned int o0 = (unsigned int)__shfl_up((int)scan[0], d, 64);
        unsigned int o1 = (unsigned int)__shfl_up((int)scan[1], d, 64);
        if (lane >= d) {
            if (o0 > scan[0]) scan[0] = o0;
            if (o1 > scan[1]) scan[1] = o1;
        }
    }
    if (lane == 63) {
        chunk_tot[2 * w]     = scan[0];
        chunk_tot[2 * w + 1] = scan[1];
    }
    __syncthreads();

    unsigned int pre0 = 0;  // max over chunks before chunk 2w
    for (int j = 0; j < 2 * w; ++j) {
        const unsigned int v = chunk_tot[j];
        if (v > pre0) pre0 = v;
    }
    const unsigned int c0t  = chunk_tot[2 * w];
    const unsigned int pre1 = pre0 > c0t ? pre0 : c0t;

    const unsigned int s0 = pre0 > scan[0] ? pre0 : scan[0];
    const unsigned int s1 = pre1 > scan[1] ? pre1 : scan[1];

    // ---- epilogue: avg_delta + mode, coalesced float2 stores (x2 outputs)
    const int   t0  = w * 128 + lane;
    const int   t1  = t0 + 64;
    const float ts0 = ts[b * SEQ_L];
    const float a0  = (ts[b * SEQ_L + t0] - ts0) / (float)(t0 + 1);
    const float a1  = (ts[b * SEQ_L + t1] - ts0) / (float)(t1 + 1);

    const float2 o0 = make_float2(a0, (float)(999 - (int)(s0 & 1023u)));
    const float2 o1 = make_float2(a1, (float)(999 - (int)(s1 & 1023u)));

    float2* o2 = (float2*)out;
    o2[b * SEQ_L + t0] = o0;                      // output 0
    o2[b * SEQ_L + t1] = o1;
    o2[SEQ_B * SEQ_L + b * SEQ_L + t0] = o0;      // output 1 (same flat data)
    o2[SEQ_B * SEQ_L + b * SEQ_L + t1] = o1;
}

extern "C" void kernel_launch(void* const* d_in, const int* in_sizes, int n_in,
                              void* d_out, int out_size, void* d_ws, size_t ws_size,
                              hipStream_t stream) {
    const float* ts     = (const float*)d_in[0];
    const int*   labels = (const int*)d_in[1];
    float*       out    = (float*)d_out;

    mpe_kernel<<<dim3(SEQ_B), dim3(1024), 0, stream>>>(ts, labels, out);
}